// Round 1
// baseline (638.984 us; speedup 1.0000x reference)
//
#include <hip/hip_runtime.h>
#include <stdint.h>

// ---------------- problem constants ----------------
#define TOK    4096            // B*S tokens
#define DMODEL 1024
#define FDIM   2048
#define NEXP   8
#define MAXP   9216            // 2*TOK + 8*128 worst-case segment padding
#define MAXT   72              // MAXP / 128 row tiles
#define OUT_MAIN (TOK * DMODEL)   // floats; router logits follow (TOK*NEXP)

// meta int indices (ws)
#define IDX_CNT 0
#define IDX_CUR 8
#define IDX_SEG 16
#define IDX_NT  24
#define IDX_TE  32
#define IDX_TR  112

// ws byte offsets
#define OFF_META 0
#define OFF_TKE  1024
#define OFF_TKW  33792
#define OFF_PTOK 66560
#define OFF_PW   103424
#define OFF_XG   140288            // [MAXP][1024] bf16  (18.9 MB)
#define OFF_H    19014656          // [MAXP][2048] bf16  (37.7 MB)
// total ws use ~56.8 MB

typedef __attribute__((ext_vector_type(8))) __bf16 bf16x8;
typedef __attribute__((ext_vector_type(8))) unsigned short u16x8;
typedef __attribute__((ext_vector_type(4))) unsigned short u16x4;
typedef __attribute__((ext_vector_type(4))) float f32x4;

__device__ __forceinline__ unsigned short f2bf(float f) {
  unsigned u = __builtin_bit_cast(unsigned, f);
  u += 0x7fffu + ((u >> 16) & 1u);          // RNE
  return (unsigned short)(u >> 16);
}

__device__ __forceinline__ void async_load16(const void* g, void* l) {
  __builtin_amdgcn_global_load_lds(
      (__attribute__((address_space(1))) void*)g,
      (__attribute__((address_space(3))) void*)l, 16, 0, 0);
}

__device__ __forceinline__ bf16x8 ld_frag(const unsigned short* p) {
  return __builtin_bit_cast(bf16x8, *(const u16x8*)p);
}

__device__ __forceinline__ f32x4 zero4() { f32x4 z = {0.f, 0.f, 0.f, 0.f}; return z; }

// ---------------- router: logits = x @ gate_w^T, fp64 accumulate ----------------
__global__ void k_router(const float* __restrict__ x, const float* __restrict__ gw,
                         float* __restrict__ logits) {
  int lane = threadIdx.x & 63;
  int t = blockIdx.x * 4 + (threadIdx.x >> 6);
  double acc[NEXP];
#pragma unroll
  for (int e = 0; e < NEXP; ++e) acc[e] = 0.0;
  const float* xp = x + (size_t)t * DMODEL;
  for (int i = 0; i < DMODEL / 64; ++i) {
    int d = i * 64 + lane;
    float xv = xp[d];
#pragma unroll
    for (int e = 0; e < NEXP; ++e) acc[e] += (double)xv * (double)gw[e * DMODEL + d];
  }
#pragma unroll
  for (int e = 0; e < NEXP; ++e) {
    double v = acc[e];
#pragma unroll
    for (int off = 32; off > 0; off >>= 1) v += __shfl_down(v, off, 64);
    if (lane == 0) logits[t * NEXP + e] = (float)v;
  }
}

// ---------------- sparsemixer top-2 routing (exact reference semantics) ----------------
__global__ void k_routing(const float* __restrict__ logits, int* __restrict__ meta,
                          int* __restrict__ tk_e, float* __restrict__ tk_w) {
  int t = blockIdx.x * blockDim.x + threadIdx.x;
  float s[NEXP];
#pragma unroll
  for (int e = 0; e < NEXP; ++e) s[e] = logits[t * NEXP + e];
  // expert 1
  float max1 = s[0]; int ind1 = 0;
#pragma unroll
  for (int e = 1; e < NEXP; ++e) if (s[e] > max1) { max1 = s[e]; ind1 = e; }
  float sum1 = 0.f;
#pragma unroll
  for (int e = 0; e < NEXP; ++e) {
    float f = fmaxf(fabsf(s[e]), max1);
    if (!((max1 - s[e]) / f > 0.02f)) sum1 += expf(s[e] - max1);
  }
  float w1 = 1.f / sum1;   // softmax value at argmax
  // expert 2 (first pick masked out)
  float max2 = -3.4e38f; int ind2 = 0;
#pragma unroll
  for (int e = 0; e < NEXP; ++e) if (e != ind1 && s[e] > max2) { max2 = s[e]; ind2 = e; }
  float sum2 = 0.f;
#pragma unroll
  for (int e = 0; e < NEXP; ++e) {
    if (e == ind1) continue;
    float f = fmaxf(fabsf(s[e]), max2);
    if (!((max2 - s[e]) / f > 0.02f)) sum2 += expf(s[e] - max2);
  }
  float w2 = 1.f / sum2;
  tk_e[2 * t] = ind1; tk_e[2 * t + 1] = ind2;
  tk_w[2 * t] = w1;   tk_w[2 * t + 1] = w2;
  atomicAdd(&meta[IDX_CNT + ind1], 1);
  atomicAdd(&meta[IDX_CNT + ind2], 1);
}

// ---------------- segment scan + tile table (single thread; 8 experts) ----------------
__global__ void k_scan(int* __restrict__ meta) {
  if (threadIdx.x != 0) return;
  int off = 0, nt = 0;
  for (int e = 0; e < NEXP; ++e) {
    meta[IDX_SEG + e] = off;
    int cnt = meta[IDX_CNT + e];
    int tiles = (cnt + 127) >> 7;
    for (int j = 0; j < tiles; ++j) {
      meta[IDX_TE + nt] = e;
      meta[IDX_TR + nt] = off + (j << 7);
      ++nt;
    }
    off += tiles << 7;
  }
  meta[IDX_NT] = nt;
}

// ---------------- scatter token-expert pairs into padded segments ----------------
__global__ void k_scatter(const int* __restrict__ tk_e, const float* __restrict__ tk_w,
                          int* __restrict__ meta, int* __restrict__ ptok,
                          float* __restrict__ pw) {
  int t = blockIdx.x * blockDim.x + threadIdx.x;
#pragma unroll
  for (int k = 0; k < 2; ++k) {
    int e = tk_e[2 * t + k];
    int p = atomicAdd(&meta[IDX_CUR + e], 1);
    int r = meta[IDX_SEG + e] + p;
    ptok[r] = t;
    pw[r] = tk_w[2 * t + k];
  }
}

// ---------------- gather x rows (fp32 -> bf16) in pair order; pads -> 0 ----------------
__global__ void k_gather(const float* __restrict__ x, const int* __restrict__ ptok,
                         unsigned short* __restrict__ xg) {
  int r = blockIdx.x;
  int t = ptok[r];
  int c = threadIdx.x << 2;
  unsigned short o0 = 0, o1 = 0, o2 = 0, o3 = 0;
  if (t >= 0) {
    float4 v = *(const float4*)(x + ((size_t)t << 10) + c);
    o0 = f2bf(v.x); o1 = f2bf(v.y); o2 = f2bf(v.z); o3 = f2bf(v.w);
  }
  u16x4 o = {o0, o1, o2, o3};
  *(u16x4*)(xg + ((size_t)r << 10) + c) = o;
}

// ---------------- fused gate+up GEMM: h = silu(xg@Wg^T) * (xg@Wu^T), bf16 out ----------
__global__ __launch_bounds__(256, 2) void k_gu(
    const unsigned short* __restrict__ xg, const float* __restrict__ w_gate,
    const float* __restrict__ w_up, unsigned short* __restrict__ h,
    const int* __restrict__ meta) {
  int nt = meta[IDX_NT];
  int rt = blockIdx.y;
  if (rt >= nt) return;
  int e = meta[IDX_TE + rt];
  int row0 = meta[IDX_TR + rt];
  int n0 = blockIdx.x * 128;
  const float* Wg = w_gate + (size_t)e * FDIM * DMODEL;
  const float* Wu = w_up + (size_t)e * FDIM * DMODEL;

  __shared__ __align__(16) unsigned short As[8192], Bg[8192], Bu[8192];

  int tid = threadIdx.x;
  int lane = tid & 63;
  int w = tid >> 6;
  int wm = w >> 1, wn = w & 1;
  int fr = lane & 15, fq = lane >> 4;

  f32x4 accg[16], accu[16];
#pragma unroll
  for (int i = 0; i < 16; ++i) { accg[i] = zero4(); accu[i] = zero4(); }

  for (int ks = 0; ks < DMODEL / 64; ++ks) {
    int k0 = ks * 64;
    if (ks) __syncthreads();
    // A tile, fragment-ordered chunks (wave-uniform LDS base + lane*16B)
#pragma unroll
    for (int i = 0; i < 4; ++i) {
      int c = w * 4 + i;              // c = msub*2 + ksub
      int msub = c >> 1, ksub = c & 1;
      const unsigned short* gp =
          xg + (size_t)(row0 + msub * 16 + fr) * DMODEL + (k0 + ksub * 32 + fq * 8);
      async_load16(gp, &As[c * 512]);
    }
    // B tiles: fp32 load -> bf16 convert -> fragment-ordered ds_write_b128
#pragma unroll
    for (int i = 0; i < 4; ++i) {
      int tau = tid + 256 * i;
      int c = tau >> 6, l = tau & 63;
      int nrow = n0 + ((c >> 1) << 4) + (l & 15);
      int kk = k0 + ((c & 1) << 5) + ((l >> 4) << 3);
      const float* sg = Wg + (size_t)nrow * DMODEL + kk;
      const float* su = Wu + (size_t)nrow * DMODEL + kk;
      float4 g0 = *(const float4*)sg;
      float4 g1 = *(const float4*)(sg + 4);
      float4 u0 = *(const float4*)su;
      float4 u1 = *(const float4*)(su + 4);
      u16x8 vg = {f2bf(g0.x), f2bf(g0.y), f2bf(g0.z), f2bf(g0.w),
                  f2bf(g1.x), f2bf(g1.y), f2bf(g1.z), f2bf(g1.w)};
      u16x8 vu = {f2bf(u0.x), f2bf(u0.y), f2bf(u0.z), f2bf(u0.w),
                  f2bf(u1.x), f2bf(u1.y), f2bf(u1.z), f2bf(u1.w)};
      *(u16x8*)&Bg[c * 512 + l * 8] = vg;
      *(u16x8*)&Bu[c * 512 + l * 8] = vu;
    }
    __syncthreads();
#pragma unroll
    for (int ksub = 0; ksub < 2; ++ksub) {
      bf16x8 a[4];
#pragma unroll
      for (int ms = 0; ms < 4; ++ms)
        a[ms] = ld_frag(&As[(((wm * 4 + ms) << 1) + ksub) * 512 + lane * 8]);
#pragma unroll
      for (int ns = 0; ns < 4; ++ns) {
        bf16x8 vg = ld_frag(&Bg[(((wn * 4 + ns) << 1) + ksub) * 512 + lane * 8]);
        bf16x8 vu = ld_frag(&Bu[(((wn * 4 + ns) << 1) + ksub) * 512 + lane * 8]);
#pragma unroll
        for (int ms = 0; ms < 4; ++ms) {
          accg[ms * 4 + ns] =
              __builtin_amdgcn_mfma_f32_16x16x32_bf16(a[ms], vg, accg[ms * 4 + ns], 0, 0, 0);
          accu[ms * 4 + ns] =
              __builtin_amdgcn_mfma_f32_16x16x32_bf16(a[ms], vu, accu[ms * 4 + ns], 0, 0, 0);
        }
      }
    }
  }
  // epilogue: h = silu(g) * u  (C/D layout: col=lane&15, row=quad*4+i)
#pragma unroll
  for (int ms = 0; ms < 4; ++ms) {
#pragma unroll
    for (int ns = 0; ns < 4; ++ns) {
      f32x4 g4 = accg[ms * 4 + ns], u4 = accu[ms * 4 + ns];
#pragma unroll
      for (int i = 0; i < 4; ++i) {
        int lrow = wm * 64 + ms * 16 + fq * 4 + i;
        int col = n0 + wn * 64 + ns * 16 + fr;
        float gv = g4[i], uv = u4[i];
        float hv = gv * uv / (1.f + __expf(-gv));
        h[(size_t)(row0 + lrow) * FDIM + col] = f2bf(hv);
      }
    }
  }
}

// ---------------- down GEMM: out[tok] += pw * (h @ Wd^T) ----------------
__global__ __launch_bounds__(256, 2) void k_down(
    const unsigned short* __restrict__ h, const float* __restrict__ w_down,
    float* __restrict__ out, const int* __restrict__ meta,
    const int* __restrict__ ptok, const float* __restrict__ pw) {
  int nt = meta[IDX_NT];
  int rt = blockIdx.y;
  if (rt >= nt) return;
  int e = meta[IDX_TE + rt];
  int row0 = meta[IDX_TR + rt];
  int d0 = blockIdx.x * 128;
  const float* Wd = w_down + (size_t)e * DMODEL * FDIM;

  __shared__ __align__(16) unsigned short Ah[8192], Bd[8192];
  __shared__ int stok[128];
  __shared__ float sw[128];

  int tid = threadIdx.x;
  int lane = tid & 63;
  int w = tid >> 6;
  int wm = w >> 1, wn = w & 1;
  int fr = lane & 15, fq = lane >> 4;

  if (tid < 128) { stok[tid] = ptok[row0 + tid]; sw[tid] = pw[row0 + tid]; }

  f32x4 acc[16];
#pragma unroll
  for (int i = 0; i < 16; ++i) acc[i] = zero4();

  for (int ks = 0; ks < FDIM / 64; ++ks) {
    int k0 = ks * 64;
    if (ks) __syncthreads();
#pragma unroll
    for (int i = 0; i < 4; ++i) {
      int c = w * 4 + i;
      int msub = c >> 1, ksub = c & 1;
      const unsigned short* gp =
          h + (size_t)(row0 + msub * 16 + fr) * FDIM + (k0 + ksub * 32 + fq * 8);
      async_load16(gp, &Ah[c * 512]);
    }
#pragma unroll
    for (int i = 0; i < 4; ++i) {
      int tau = tid + 256 * i;
      int c = tau >> 6, l = tau & 63;
      int drow = d0 + ((c >> 1) << 4) + (l & 15);
      int kk = k0 + ((c & 1) << 5) + ((l >> 4) << 3);
      const float* sd = Wd + (size_t)drow * FDIM + kk;
      float4 b0 = *(const float4*)sd;
      float4 b1 = *(const float4*)(sd + 4);
      u16x8 vb = {f2bf(b0.x), f2bf(b0.y), f2bf(b0.z), f2bf(b0.w),
                  f2bf(b1.x), f2bf(b1.y), f2bf(b1.z), f2bf(b1.w)};
      *(u16x8*)&Bd[c * 512 + l * 8] = vb;
    }
    __syncthreads();
#pragma unroll
    for (int ksub = 0; ksub < 2; ++ksub) {
      bf16x8 a[4];
#pragma unroll
      for (int ms = 0; ms < 4; ++ms)
        a[ms] = ld_frag(&Ah[(((wm * 4 + ms) << 1) + ksub) * 512 + lane * 8]);
#pragma unroll
      for (int ns = 0; ns < 4; ++ns) {
        bf16x8 vb = ld_frag(&Bd[(((wn * 4 + ns) << 1) + ksub) * 512 + lane * 8]);
#pragma unroll
        for (int ms = 0; ms < 4; ++ms)
          acc[ms * 4 + ns] =
              __builtin_amdgcn_mfma_f32_16x16x32_bf16(a[ms], vb, acc[ms * 4 + ns], 0, 0, 0);
      }
    }
  }
  // epilogue: scale by pair weight, atomicAdd into out (exactly 2 adds/element)
#pragma unroll
  for (int ms = 0; ms < 4; ++ms) {
#pragma unroll
    for (int ns = 0; ns < 4; ++ns) {
      f32x4 v4 = acc[ms * 4 + ns];
#pragma unroll
      for (int i = 0; i < 4; ++i) {
        int lrow = wm * 64 + ms * 16 + fq * 4 + i;
        int col = d0 + wn * 64 + ns * 16 + fr;
        int t = stok[lrow];
        if (t >= 0) atomicAdd(&out[(size_t)t * DMODEL + col], v4[i] * sw[lrow]);
      }
    }
  }
}

// ---------------- launch ----------------
extern "C" void kernel_launch(void* const* d_in, const int* in_sizes, int n_in,
                              void* d_out, int out_size, void* d_ws, size_t ws_size,
                              hipStream_t stream) {
  const float* x  = (const float*)d_in[0];
  const float* gw = (const float*)d_in[1];
  const float* wg = (const float*)d_in[2];
  const float* wu = (const float*)d_in[3];
  const float* wd = (const float*)d_in[4];
  float* out = (float*)d_out;
  float* logits = out + OUT_MAIN;

  char* wsb = (char*)d_ws;
  int* meta = (int*)(wsb + OFF_META);
  int* tk_e = (int*)(wsb + OFF_TKE);
  float* tk_w = (float*)(wsb + OFF_TKW);
  int* ptok = (int*)(wsb + OFF_PTOK);
  float* pw = (float*)(wsb + OFF_PW);
  unsigned short* xg = (unsigned short*)(wsb + OFF_XG);
  unsigned short* h = (unsigned short*)(wsb + OFF_H);

  hipMemsetAsync(out, 0, (size_t)OUT_MAIN * sizeof(float), stream);
  hipMemsetAsync(meta, 0, 64, stream);                       // counts + cursors
  hipMemsetAsync(ptok, 0xFF, MAXP * sizeof(int), stream);    // -1 = padding
  hipMemsetAsync(pw, 0, MAXP * sizeof(float), stream);

  k_router<<<TOK / 4, 256, 0, stream>>>(x, gw, logits);
  k_routing<<<TOK / 256, 256, 0, stream>>>(logits, meta, tk_e, tk_w);
  k_scan<<<1, 64, 0, stream>>>(meta);
  k_scatter<<<TOK / 256, 256, 0, stream>>>(tk_e, tk_w, meta, ptok, pw);
  k_gather<<<MAXP, 256, 0, stream>>>(x, ptok, xg);
  k_gu<<<dim3(FDIM / 128, MAXT), 256, 0, stream>>>(xg, wg, wu, h, meta);
  k_down<<<dim3(DMODEL / 128, MAXT), 256, 0, stream>>>(h, wd, out, meta, ptok, pw);
}

// Round 2
// 623.580 us; speedup vs baseline: 1.0247x; 1.0247x over previous
//
#include <hip/hip_runtime.h>
#include <stdint.h>

// ---------------- problem constants ----------------
#define TOK    4096            // B*S tokens
#define DMODEL 1024
#define FDIM   2048
#define NEXP   8
#define MAXP   9216            // 2*TOK + 8*128 worst-case segment padding
#define MAXT   72              // MAXP / 128 row tiles
#define OUT_MAIN (TOK * DMODEL)   // floats; router logits follow (TOK*NEXP)

// meta int indices (ws)
#define IDX_CNT 0
#define IDX_CUR 8
#define IDX_SEG 16
#define IDX_NT  24
#define IDX_TE  32
#define IDX_TR  112

// ws byte offsets
#define OFF_META 0
#define OFF_TKE  1024
#define OFF_TKW  33792
#define OFF_PTOK 66560
#define OFF_PW   103424
#define OFF_XG   140288            // [MAXP][1024] bf16  (18.9 MB)
#define OFF_H    19014656          // [MAXP][2048] bf16  (37.7 MB)
#define OFF_WGB  56763392          // [E][F][D] bf16 (32 MB)
#define OFF_WUB  90317824          // [E][F][D] bf16 (32 MB)
#define OFF_WDB  123872256         // [E][D][F] bf16 (32 MB)
#define WS_NEED  157426688         // ~150.1 MB total

typedef __attribute__((ext_vector_type(8))) __bf16 bf16x8;
typedef __attribute__((ext_vector_type(8))) unsigned short u16x8;
typedef __attribute__((ext_vector_type(4))) unsigned short u16x4;
typedef __attribute__((ext_vector_type(4))) float f32x4;

__device__ __forceinline__ unsigned short f2bf(float f) {
  unsigned u = __builtin_bit_cast(unsigned, f);
  u += 0x7fffu + ((u >> 16) & 1u);          // RNE
  return (unsigned short)(u >> 16);
}

__device__ __forceinline__ void async_load16(const void* g, void* l) {
  __builtin_amdgcn_global_load_lds(
      (__attribute__((address_space(1))) void*)g,
      (__attribute__((address_space(3))) void*)l, 16, 0, 0);
}

__device__ __forceinline__ bf16x8 ld_frag(const unsigned short* p) {
  return __builtin_bit_cast(bf16x8, *(const u16x8*)p);
}

__device__ __forceinline__ f32x4 zero4() { f32x4 z = {0.f, 0.f, 0.f, 0.f}; return z; }

// ---------------- weight convert fp32 -> bf16 (memory-bound, once) ----------------
__global__ void k_conv(const float* __restrict__ src, unsigned short* __restrict__ dst) {
  size_t i = ((size_t)blockIdx.x * 256 + threadIdx.x) * 8;
  float4 a = *(const float4*)(src + i);
  float4 b = *(const float4*)(src + i + 4);
  u16x8 v = {f2bf(a.x), f2bf(a.y), f2bf(a.z), f2bf(a.w),
             f2bf(b.x), f2bf(b.y), f2bf(b.z), f2bf(b.w)};
  *(u16x8*)(dst + i) = v;
}

// ---------------- router: logits = x @ gate_w^T, fp64 accumulate ----------------
__global__ void k_router(const float* __restrict__ x, const float* __restrict__ gw,
                         float* __restrict__ logits) {
  int lane = threadIdx.x & 63;
  int t = blockIdx.x * 4 + (threadIdx.x >> 6);
  double acc[NEXP];
#pragma unroll
  for (int e = 0; e < NEXP; ++e) acc[e] = 0.0;
  const float* xp = x + (size_t)t * DMODEL;
  for (int i = 0; i < DMODEL / 64; ++i) {
    int d = i * 64 + lane;
    float xv = xp[d];
#pragma unroll
    for (int e = 0; e < NEXP; ++e) acc[e] += (double)xv * (double)gw[e * DMODEL + d];
  }
#pragma unroll
  for (int e = 0; e < NEXP; ++e) {
    double v = acc[e];
#pragma unroll
    for (int off = 32; off > 0; off >>= 1) v += __shfl_down(v, off, 64);
    if (lane == 0) logits[t * NEXP + e] = (float)v;
  }
}

// ---------------- sparsemixer top-2 routing (exact reference semantics) ----------------
__global__ void k_routing(const float* __restrict__ logits, int* __restrict__ meta,
                          int* __restrict__ tk_e, float* __restrict__ tk_w) {
  int t = blockIdx.x * blockDim.x + threadIdx.x;
  float s[NEXP];
#pragma unroll
  for (int e = 0; e < NEXP; ++e) s[e] = logits[t * NEXP + e];
  float max1 = s[0]; int ind1 = 0;
#pragma unroll
  for (int e = 1; e < NEXP; ++e) if (s[e] > max1) { max1 = s[e]; ind1 = e; }
  float sum1 = 0.f;
#pragma unroll
  for (int e = 0; e < NEXP; ++e) {
    float f = fmaxf(fabsf(s[e]), max1);
    if (!((max1 - s[e]) / f > 0.02f)) sum1 += expf(s[e] - max1);
  }
  float w1 = 1.f / sum1;
  float max2 = -3.4e38f; int ind2 = 0;
#pragma unroll
  for (int e = 0; e < NEXP; ++e) if (e != ind1 && s[e] > max2) { max2 = s[e]; ind2 = e; }
  float sum2 = 0.f;
#pragma unroll
  for (int e = 0; e < NEXP; ++e) {
    if (e == ind1) continue;
    float f = fmaxf(fabsf(s[e]), max2);
    if (!((max2 - s[e]) / f > 0.02f)) sum2 += expf(s[e] - max2);
  }
  float w2 = 1.f / sum2;
  tk_e[2 * t] = ind1; tk_e[2 * t + 1] = ind2;
  tk_w[2 * t] = w1;   tk_w[2 * t + 1] = w2;
  atomicAdd(&meta[IDX_CNT + ind1], 1);
  atomicAdd(&meta[IDX_CNT + ind2], 1);
}

// ---------------- segment scan + tile table ----------------
__global__ void k_scan(int* __restrict__ meta) {
  if (threadIdx.x != 0) return;
  int off = 0, nt = 0;
  for (int e = 0; e < NEXP; ++e) {
    meta[IDX_SEG + e] = off;
    int cnt = meta[IDX_CNT + e];
    int tiles = (cnt + 127) >> 7;
    for (int j = 0; j < tiles; ++j) {
      meta[IDX_TE + nt] = e;
      meta[IDX_TR + nt] = off + (j << 7);
      ++nt;
    }
    off += tiles << 7;
  }
  meta[IDX_NT] = nt;
}

// ---------------- scatter pairs into padded segments ----------------
__global__ void k_scatter(const int* __restrict__ tk_e, const float* __restrict__ tk_w,
                          int* __restrict__ meta, int* __restrict__ ptok,
                          float* __restrict__ pw) {
  int t = blockIdx.x * blockDim.x + threadIdx.x;
#pragma unroll
  for (int k = 0; k < 2; ++k) {
    int e = tk_e[2 * t + k];
    int p = atomicAdd(&meta[IDX_CUR + e], 1);
    int r = meta[IDX_SEG + e] + p;
    ptok[r] = t;
    pw[r] = tk_w[2 * t + k];
  }
}

// ---------------- gather x rows (fp32 -> bf16) in pair order; pads -> 0 ----------------
__global__ void k_gather(const float* __restrict__ x, const int* __restrict__ ptok,
                         unsigned short* __restrict__ xg) {
  int r = blockIdx.x;
  int t = ptok[r];
  int c = threadIdx.x << 2;
  unsigned short o0 = 0, o1 = 0, o2 = 0, o3 = 0;
  if (t >= 0) {
    float4 v = *(const float4*)(x + ((size_t)t << 10) + c);
    o0 = f2bf(v.x); o1 = f2bf(v.y); o2 = f2bf(v.z); o3 = f2bf(v.w);
  }
  u16x4 o = {o0, o1, o2, o3};
  *(u16x4*)(xg + ((size_t)r << 10) + c) = o;
}

// ---------------- fused gate+up GEMM: h = silu(xg@Wg^T) * (xg@Wu^T) ----------------
template <bool PRE>
__global__ __launch_bounds__(256, 3) void k_gu(
    const unsigned short* __restrict__ xg,
    const float* __restrict__ w_gate32, const float* __restrict__ w_up32,
    const unsigned short* __restrict__ w_gateb, const unsigned short* __restrict__ w_upb,
    unsigned short* __restrict__ h, const int* __restrict__ meta) {
  int nt = meta[IDX_NT];
  int rt = blockIdx.y;
  if (rt >= nt) return;
  int e = meta[IDX_TE + rt];
  int row0 = meta[IDX_TR + rt];
  int n0 = blockIdx.x * 128;

  __shared__ __align__(16) unsigned short As[8192], Bg[8192], Bu[8192];

  int tid = threadIdx.x;
  int lane = tid & 63;
  int w = tid >> 6;
  int wm = w >> 1, wn = w & 1;
  int fr = lane & 15, fq = lane >> 4;

  f32x4 accg[16], accu[16];
#pragma unroll
  for (int i = 0; i < 16; ++i) { accg[i] = zero4(); accu[i] = zero4(); }

  for (int ks = 0; ks < DMODEL / 64; ++ks) {
    int k0 = ks * 64;
    if (ks) __syncthreads();
    // A tile: fragment-ordered async DMA chunks
#pragma unroll
    for (int i = 0; i < 4; ++i) {
      int c = w * 4 + i;              // c = msub*2 + ksub
      int msub = c >> 1, ksub = c & 1;
      const unsigned short* gp =
          xg + (size_t)(row0 + msub * 16 + fr) * DMODEL + (k0 + ksub * 32 + fq * 8);
      async_load16(gp, &As[c * 512]);
    }
    if constexpr (PRE) {
      const unsigned short* Wg = w_gateb + (size_t)e * FDIM * DMODEL;
      const unsigned short* Wu = w_upb + (size_t)e * FDIM * DMODEL;
#pragma unroll
      for (int i = 0; i < 4; ++i) {
        int c = w * 4 + i;
        int nrow = n0 + ((c >> 1) << 4) + fr;
        int kk = k0 + ((c & 1) << 5) + (fq << 3);
        size_t off = (size_t)nrow * DMODEL + kk;
        async_load16(Wg + off, &Bg[c * 512]);
        async_load16(Wu + off, &Bu[c * 512]);
      }
    } else {
      const float* Wg = w_gate32 + (size_t)e * FDIM * DMODEL;
      const float* Wu = w_up32 + (size_t)e * FDIM * DMODEL;
#pragma unroll
      for (int i = 0; i < 4; ++i) {
        int tau = tid + 256 * i;
        int c = tau >> 6, l = tau & 63;
        int nrow = n0 + ((c >> 1) << 4) + (l & 15);
        int kk = k0 + ((c & 1) << 5) + ((l >> 4) << 3);
        const float* sg = Wg + (size_t)nrow * DMODEL + kk;
        const float* su = Wu + (size_t)nrow * DMODEL + kk;
        float4 g0 = *(const float4*)sg;
        float4 g1 = *(const float4*)(sg + 4);
        float4 u0 = *(const float4*)su;
        float4 u1 = *(const float4*)(su + 4);
        u16x8 vg = {f2bf(g0.x), f2bf(g0.y), f2bf(g0.z), f2bf(g0.w),
                    f2bf(g1.x), f2bf(g1.y), f2bf(g1.z), f2bf(g1.w)};
        u16x8 vu = {f2bf(u0.x), f2bf(u0.y), f2bf(u0.z), f2bf(u0.w),
                    f2bf(u1.x), f2bf(u1.y), f2bf(u1.z), f2bf(u1.w)};
        *(u16x8*)&Bg[c * 512 + l * 8] = vg;
        *(u16x8*)&Bu[c * 512 + l * 8] = vu;
      }
    }
    __syncthreads();
#pragma unroll
    for (int ksub = 0; ksub < 2; ++ksub) {
      bf16x8 a[4];
#pragma unroll
      for (int ms = 0; ms < 4; ++ms)
        a[ms] = ld_frag(&As[(((wm * 4 + ms) << 1) + ksub) * 512 + lane * 8]);
#pragma unroll
      for (int ns = 0; ns < 4; ++ns) {
        bf16x8 vg = ld_frag(&Bg[(((wn * 4 + ns) << 1) + ksub) * 512 + lane * 8]);
        bf16x8 vu = ld_frag(&Bu[(((wn * 4 + ns) << 1) + ksub) * 512 + lane * 8]);
#pragma unroll
        for (int ms = 0; ms < 4; ++ms) {
          accg[ms * 4 + ns] =
              __builtin_amdgcn_mfma_f32_16x16x32_bf16(a[ms], vg, accg[ms * 4 + ns], 0, 0, 0);
          accu[ms * 4 + ns] =
              __builtin_amdgcn_mfma_f32_16x16x32_bf16(a[ms], vu, accu[ms * 4 + ns], 0, 0, 0);
        }
      }
    }
  }
  // epilogue: h = silu(g) * u  (C/D layout: col=lane&15, row=quad*4+i)
#pragma unroll
  for (int ms = 0; ms < 4; ++ms) {
#pragma unroll
    for (int ns = 0; ns < 4; ++ns) {
      f32x4 g4 = accg[ms * 4 + ns], u4 = accu[ms * 4 + ns];
#pragma unroll
      for (int i = 0; i < 4; ++i) {
        int lrow = wm * 64 + ms * 16 + fq * 4 + i;
        int col = n0 + wn * 64 + ns * 16 + fr;
        float gv = g4[i], uv = u4[i];
        float hv = gv * uv / (1.f + __expf(-gv));
        h[(size_t)(row0 + lrow) * FDIM + col] = f2bf(hv);
      }
    }
  }
}

// ---------------- down GEMM: out[tok] += pw * (h @ Wd^T) ----------------
template <bool PRE>
__global__ __launch_bounds__(256, 3) void k_down(
    const unsigned short* __restrict__ h, const float* __restrict__ w_down32,
    const unsigned short* __restrict__ w_downb, float* __restrict__ out,
    const int* __restrict__ meta, const int* __restrict__ ptok,
    const float* __restrict__ pw) {
  int nt = meta[IDX_NT];
  int rt = blockIdx.y;
  if (rt >= nt) return;
  int e = meta[IDX_TE + rt];
  int row0 = meta[IDX_TR + rt];
  int d0 = blockIdx.x * 128;

  __shared__ __align__(16) unsigned short Ah[8192], Bd[8192];
  __shared__ int stok[128];
  __shared__ float sw[128];

  int tid = threadIdx.x;
  int lane = tid & 63;
  int w = tid >> 6;
  int wm = w >> 1, wn = w & 1;
  int fr = lane & 15, fq = lane >> 4;

  if (tid < 128) { stok[tid] = ptok[row0 + tid]; sw[tid] = pw[row0 + tid]; }

  f32x4 acc[16];
#pragma unroll
  for (int i = 0; i < 16; ++i) acc[i] = zero4();

  for (int ks = 0; ks < FDIM / 64; ++ks) {
    int k0 = ks * 64;
    if (ks) __syncthreads();
#pragma unroll
    for (int i = 0; i < 4; ++i) {
      int c = w * 4 + i;
      int msub = c >> 1, ksub = c & 1;
      const unsigned short* gp =
          h + (size_t)(row0 + msub * 16 + fr) * FDIM + (k0 + ksub * 32 + fq * 8);
      async_load16(gp, &Ah[c * 512]);
    }
    if constexpr (PRE) {
      const unsigned short* Wd = w_downb + (size_t)e * DMODEL * FDIM;
#pragma unroll
      for (int i = 0; i < 4; ++i) {
        int c = w * 4 + i;
        int drow = d0 + ((c >> 1) << 4) + fr;
        int kk = k0 + ((c & 1) << 5) + (fq << 3);
        async_load16(Wd + (size_t)drow * FDIM + kk, &Bd[c * 512]);
      }
    } else {
      const float* Wd = w_down32 + (size_t)e * DMODEL * FDIM;
#pragma unroll
      for (int i = 0; i < 4; ++i) {
        int tau = tid + 256 * i;
        int c = tau >> 6, l = tau & 63;
        int drow = d0 + ((c >> 1) << 4) + (l & 15);
        int kk = k0 + ((c & 1) << 5) + ((l >> 4) << 3);
        const float* sd = Wd + (size_t)drow * FDIM + kk;
        float4 b0 = *(const float4*)sd;
        float4 b1 = *(const float4*)(sd + 4);
        u16x8 vb = {f2bf(b0.x), f2bf(b0.y), f2bf(b0.z), f2bf(b0.w),
                    f2bf(b1.x), f2bf(b1.y), f2bf(b1.z), f2bf(b1.w)};
        *(u16x8*)&Bd[c * 512 + l * 8] = vb;
      }
    }
    __syncthreads();
#pragma unroll
    for (int ksub = 0; ksub < 2; ++ksub) {
      bf16x8 a[4];
#pragma unroll
      for (int ms = 0; ms < 4; ++ms)
        a[ms] = ld_frag(&Ah[(((wm * 4 + ms) << 1) + ksub) * 512 + lane * 8]);
#pragma unroll
      for (int ns = 0; ns < 4; ++ns) {
        bf16x8 vb = ld_frag(&Bd[(((wn * 4 + ns) << 1) + ksub) * 512 + lane * 8]);
#pragma unroll
        for (int ms = 0; ms < 4; ++ms)
          acc[ms * 4 + ns] =
              __builtin_amdgcn_mfma_f32_16x16x32_bf16(a[ms], vb, acc[ms * 4 + ns], 0, 0, 0);
      }
    }
  }
  // epilogue: scale by pair weight, atomicAdd into out (exactly 2 adds/element)
#pragma unroll
  for (int ms = 0; ms < 4; ++ms) {
#pragma unroll
    for (int ns = 0; ns < 4; ++ns) {
      f32x4 v4 = acc[ms * 4 + ns];
#pragma unroll
      for (int i = 0; i < 4; ++i) {
        int lrow = wm * 64 + ms * 16 + fq * 4 + i;
        int col = d0 + wn * 64 + ns * 16 + fr;
        int t = stok[lrow];
        if (t >= 0) atomicAdd(&out[(size_t)t * DMODEL + col], v4[i] * sw[lrow]);
      }
    }
  }
}

// ---------------- launch ----------------
extern "C" void kernel_launch(void* const* d_in, const int* in_sizes, int n_in,
                              void* d_out, int out_size, void* d_ws, size_t ws_size,
                              hipStream_t stream) {
  const float* x  = (const float*)d_in[0];
  const float* gw = (const float*)d_in[1];
  const float* wg = (const float*)d_in[2];
  const float* wu = (const float*)d_in[3];
  const float* wd = (const float*)d_in[4];
  float* out = (float*)d_out;
  float* logits = out + OUT_MAIN;

  char* wsb = (char*)d_ws;
  int* meta = (int*)(wsb + OFF_META);
  int* tk_e = (int*)(wsb + OFF_TKE);
  float* tk_w = (float*)(wsb + OFF_TKW);
  int* ptok = (int*)(wsb + OFF_PTOK);
  float* pw = (float*)(wsb + OFF_PW);
  unsigned short* xg = (unsigned short*)(wsb + OFF_XG);
  unsigned short* h = (unsigned short*)(wsb + OFF_H);
  unsigned short* wgb = (unsigned short*)(wsb + OFF_WGB);
  unsigned short* wub = (unsigned short*)(wsb + OFF_WUB);
  unsigned short* wdb = (unsigned short*)(wsb + OFF_WDB);

  bool pre = ws_size >= (size_t)WS_NEED;

  hipMemsetAsync(out, 0, (size_t)OUT_MAIN * sizeof(float), stream);
  hipMemsetAsync(meta, 0, 64, stream);
  hipMemsetAsync(ptok, 0xFF, MAXP * sizeof(int), stream);
  hipMemsetAsync(pw, 0, MAXP * sizeof(float), stream);

  if (pre) {
    // 8*2048*1024 = 16.78M elems per tensor, 8 per thread -> 8192 blocks
    k_conv<<<8192, 256, 0, stream>>>(wg, wgb);
    k_conv<<<8192, 256, 0, stream>>>(wu, wub);
    k_conv<<<8192, 256, 0, stream>>>(wd, wdb);
  }

  k_router<<<TOK / 4, 256, 0, stream>>>(x, gw, logits);
  k_routing<<<TOK / 256, 256, 0, stream>>>(logits, meta, tk_e, tk_w);
  k_scan<<<1, 64, 0, stream>>>(meta);
  k_scatter<<<TOK / 256, 256, 0, stream>>>(tk_e, tk_w, meta, ptok, pw);
  k_gather<<<MAXP, 256, 0, stream>>>(x, ptok, xg);
  if (pre) {
    k_gu<true><<<dim3(FDIM / 128, MAXT), 256, 0, stream>>>(xg, wg, wu, wgb, wub, h, meta);
    k_down<true><<<dim3(DMODEL / 128, MAXT), 256, 0, stream>>>(h, wd, wdb, out, meta, ptok, pw);
  } else {
    k_gu<false><<<dim3(FDIM / 128, MAXT), 256, 0, stream>>>(xg, wg, wu, wgb, wub, h, meta);
    k_down<false><<<dim3(DMODEL / 128, MAXT), 256, 0, stream>>>(h, wd, wdb, out, meta, ptok, pw);
  }
}

// Round 3
// 590.716 us; speedup vs baseline: 1.0817x; 1.0556x over previous
//
#include <hip/hip_runtime.h>
#include <stdint.h>

// ---------------- problem constants ----------------
#define TOK    4096            // B*S tokens
#define DMODEL 1024
#define FDIM   2048
#define NEXP   8
#define MAXP   9216            // 2*TOK + 8*128 worst-case segment padding
#define MAXT   72              // MAXP / 128 row tiles
#define OUT_MAIN (TOK * DMODEL)   // floats; router logits follow (TOK*NEXP)

// meta int indices (ws)
#define IDX_CNT 0
#define IDX_CUR 8
#define IDX_SEG 16
#define IDX_NT  24
#define IDX_TE  32
#define IDX_TR  112

// ws byte offsets
#define OFF_META 0
#define OFF_TKE  1024
#define OFF_TKW  33792
#define OFF_PTOK 66560
#define OFF_PW   103424
#define OFF_XG   140288            // [MAXP][1024] bf16  (18.9 MB)
#define OFF_H    19014656          // [MAXP][2048] bf16  (37.7 MB)
#define OFF_WGB  56763392          // [E][F][D] bf16 (32 MB)
#define OFF_WUB  90317824          // [E][F][D] bf16 (32 MB)
#define OFF_WDB  123872256         // [E][D][F] bf16 (32 MB)
#define OFF_PV   OFF_WGB           // [MAXP][1024] fp32 (37.7 MB) — aliases wgb+wub,
                                   // which are dead once k_gu completes (same stream)
#define OFF_RPOS 157426688         // [2*TOK] int (32 KB)
#define WS_NEED  157459456

typedef __attribute__((ext_vector_type(8))) __bf16 bf16x8;
typedef __attribute__((ext_vector_type(8))) unsigned short u16x8;
typedef __attribute__((ext_vector_type(4))) unsigned short u16x4;
typedef __attribute__((ext_vector_type(4))) float f32x4;

__device__ __forceinline__ unsigned short f2bf(float f) {
  unsigned u = __builtin_bit_cast(unsigned, f);
  u += 0x7fffu + ((u >> 16) & 1u);          // RNE
  return (unsigned short)(u >> 16);
}

__device__ __forceinline__ void async_load16(const void* g, void* l) {
  __builtin_amdgcn_global_load_lds(
      (__attribute__((address_space(1))) void*)g,
      (__attribute__((address_space(3))) void*)l, 16, 0, 0);
}

__device__ __forceinline__ bf16x8 ld_frag(const unsigned short* p) {
  return __builtin_bit_cast(bf16x8, *(const u16x8*)p);
}

__device__ __forceinline__ f32x4 zero4() { f32x4 z = {0.f, 0.f, 0.f, 0.f}; return z; }

// ---------------- weight convert fp32 -> bf16 (memory-bound, once) ----------------
__global__ void k_conv(const float* __restrict__ src, unsigned short* __restrict__ dst) {
  size_t i = ((size_t)blockIdx.x * 256 + threadIdx.x) * 8;
  float4 a = *(const float4*)(src + i);
  float4 b = *(const float4*)(src + i + 4);
  u16x8 v = {f2bf(a.x), f2bf(a.y), f2bf(a.z), f2bf(a.w),
             f2bf(b.x), f2bf(b.y), f2bf(b.z), f2bf(b.w)};
  *(u16x8*)(dst + i) = v;
}

// ---------------- router: logits = x @ gate_w^T, fp64 accumulate ----------------
__global__ void k_router(const float* __restrict__ x, const float* __restrict__ gw,
                         float* __restrict__ logits) {
  int lane = threadIdx.x & 63;
  int t = blockIdx.x * 4 + (threadIdx.x >> 6);
  double acc[NEXP];
#pragma unroll
  for (int e = 0; e < NEXP; ++e) acc[e] = 0.0;
  const float* xp = x + (size_t)t * DMODEL;
  for (int i = 0; i < DMODEL / 64; ++i) {
    int d = i * 64 + lane;
    float xv = xp[d];
#pragma unroll
    for (int e = 0; e < NEXP; ++e) acc[e] += (double)xv * (double)gw[e * DMODEL + d];
  }
#pragma unroll
  for (int e = 0; e < NEXP; ++e) {
    double v = acc[e];
#pragma unroll
    for (int off = 32; off > 0; off >>= 1) v += __shfl_down(v, off, 64);
    if (lane == 0) logits[t * NEXP + e] = (float)v;
  }
}

// ---------------- sparsemixer top-2 routing (exact reference semantics) ----------------
__global__ void k_routing(const float* __restrict__ logits, int* __restrict__ meta,
                          int* __restrict__ tk_e, float* __restrict__ tk_w) {
  int t = blockIdx.x * blockDim.x + threadIdx.x;
  float s[NEXP];
#pragma unroll
  for (int e = 0; e < NEXP; ++e) s[e] = logits[t * NEXP + e];
  float max1 = s[0]; int ind1 = 0;
#pragma unroll
  for (int e = 1; e < NEXP; ++e) if (s[e] > max1) { max1 = s[e]; ind1 = e; }
  float sum1 = 0.f;
#pragma unroll
  for (int e = 0; e < NEXP; ++e) {
    float f = fmaxf(fabsf(s[e]), max1);
    if (!((max1 - s[e]) / f > 0.02f)) sum1 += expf(s[e] - max1);
  }
  float w1 = 1.f / sum1;
  float max2 = -3.4e38f; int ind2 = 0;
#pragma unroll
  for (int e = 0; e < NEXP; ++e) if (e != ind1 && s[e] > max2) { max2 = s[e]; ind2 = e; }
  float sum2 = 0.f;
#pragma unroll
  for (int e = 0; e < NEXP; ++e) {
    if (e == ind1) continue;
    float f = fmaxf(fabsf(s[e]), max2);
    if (!((max2 - s[e]) / f > 0.02f)) sum2 += expf(s[e] - max2);
  }
  float w2 = 1.f / sum2;
  tk_e[2 * t] = ind1; tk_e[2 * t + 1] = ind2;
  tk_w[2 * t] = w1;   tk_w[2 * t + 1] = w2;
  atomicAdd(&meta[IDX_CNT + ind1], 1);
  atomicAdd(&meta[IDX_CNT + ind2], 1);
}

// ---------------- segment scan + tile table ----------------
__global__ void k_scan(int* __restrict__ meta) {
  if (threadIdx.x != 0) return;
  int off = 0, nt = 0;
  for (int e = 0; e < NEXP; ++e) {
    meta[IDX_SEG + e] = off;
    int cnt = meta[IDX_CNT + e];
    int tiles = (cnt + 127) >> 7;
    for (int j = 0; j < tiles; ++j) {
      meta[IDX_TE + nt] = e;
      meta[IDX_TR + nt] = off + (j << 7);
      ++nt;
    }
    off += tiles << 7;
  }
  meta[IDX_NT] = nt;
}

// ---------------- scatter pairs into padded segments (+ inverse map) ----------------
__global__ void k_scatter(const int* __restrict__ tk_e, const float* __restrict__ tk_w,
                          int* __restrict__ meta, int* __restrict__ ptok,
                          float* __restrict__ pw, int* __restrict__ rpos) {
  int t = blockIdx.x * blockDim.x + threadIdx.x;
#pragma unroll
  for (int k = 0; k < 2; ++k) {
    int e = tk_e[2 * t + k];
    int p = atomicAdd(&meta[IDX_CUR + e], 1);
    int r = meta[IDX_SEG + e] + p;
    ptok[r] = t;
    pw[r] = tk_w[2 * t + k];
    rpos[2 * t + k] = r;
  }
}

// ---------------- gather x rows (fp32 -> bf16) in pair order; pads -> 0 ----------------
__global__ void k_gather(const float* __restrict__ x, const int* __restrict__ ptok,
                         unsigned short* __restrict__ xg) {
  int r = blockIdx.x;
  int t = ptok[r];
  int c = threadIdx.x << 2;
  unsigned short o0 = 0, o1 = 0, o2 = 0, o3 = 0;
  if (t >= 0) {
    float4 v = *(const float4*)(x + ((size_t)t << 10) + c);
    o0 = f2bf(v.x); o1 = f2bf(v.y); o2 = f2bf(v.z); o3 = f2bf(v.w);
  }
  u16x4 o = {o0, o1, o2, o3};
  *(u16x4*)(xg + ((size_t)r << 10) + c) = o;
}

// ---------------- fused gate+up GEMM: h = silu(xg@Wg^T) * (xg@Wu^T) ----------------
// tile M=128, N=64, BK=64; per wave: 64x32 per tensor -> acc 2x32 AGPR
template <bool PRE>
__global__ __launch_bounds__(256, 3) void k_gu(
    const unsigned short* __restrict__ xg,
    const float* __restrict__ w_gate32, const float* __restrict__ w_up32,
    const unsigned short* __restrict__ w_gateb, const unsigned short* __restrict__ w_upb,
    unsigned short* __restrict__ h, const int* __restrict__ meta) {
  int nt = meta[IDX_NT];
  int rt = blockIdx.y;
  if (rt >= nt) return;
  int e = meta[IDX_TE + rt];
  int row0 = meta[IDX_TR + rt];
  int n0 = blockIdx.x * 64;

  __shared__ __align__(16) unsigned short As[8192], Bg[4096], Bu[4096];

  int tid = threadIdx.x;
  int lane = tid & 63;
  int w = tid >> 6;
  int wm = w & 1, wn = w >> 1;
  int fr = lane & 15, fq = lane >> 4;

  f32x4 accg[8], accu[8];
#pragma unroll
  for (int i = 0; i < 8; ++i) { accg[i] = zero4(); accu[i] = zero4(); }

  for (int ks = 0; ks < DMODEL / 64; ++ks) {
    int k0 = ks * 64;
    if (ks) __syncthreads();
    // A tile: 16 fragment-ordered chunks (4 per wave), DMA
#pragma unroll
    for (int i = 0; i < 4; ++i) {
      int c = w * 4 + i;              // c = msub*2 + ksub
      int msub = c >> 1, ksub = c & 1;
      const unsigned short* gp =
          xg + (size_t)(row0 + msub * 16 + fr) * DMODEL + (k0 + ksub * 32 + fq * 8);
      async_load16(gp, &As[c * 512]);
    }
    if constexpr (PRE) {
      const unsigned short* Wg = w_gateb + (size_t)e * FDIM * DMODEL;
      const unsigned short* Wu = w_upb + (size_t)e * FDIM * DMODEL;
#pragma unroll
      for (int i = 0; i < 2; ++i) {
        int c = w * 2 + i;            // c = nsub*2 + ksub
        int nrow = n0 + ((c >> 1) << 4) + fr;
        int kk = k0 + ((c & 1) << 5) + (fq << 3);
        size_t off = (size_t)nrow * DMODEL + kk;
        async_load16(Wg + off, &Bg[c * 512]);
        async_load16(Wu + off, &Bu[c * 512]);
      }
    } else {
      const float* Wg = w_gate32 + (size_t)e * FDIM * DMODEL;
      const float* Wu = w_up32 + (size_t)e * FDIM * DMODEL;
#pragma unroll
      for (int i = 0; i < 2; ++i) {
        int tau = tid + 256 * i;
        int c = tau >> 6, l = tau & 63;
        int nrow = n0 + ((c >> 1) << 4) + (l & 15);
        int kk = k0 + ((c & 1) << 5) + ((l >> 4) << 3);
        const float* sg = Wg + (size_t)nrow * DMODEL + kk;
        const float* su = Wu + (size_t)nrow * DMODEL + kk;
        float4 g0 = *(const float4*)sg;
        float4 g1 = *(const float4*)(sg + 4);
        float4 u0 = *(const float4*)su;
        float4 u1 = *(const float4*)(su + 4);
        u16x8 vg = {f2bf(g0.x), f2bf(g0.y), f2bf(g0.z), f2bf(g0.w),
                    f2bf(g1.x), f2bf(g1.y), f2bf(g1.z), f2bf(g1.w)};
        u16x8 vu = {f2bf(u0.x), f2bf(u0.y), f2bf(u0.z), f2bf(u0.w),
                    f2bf(u1.x), f2bf(u1.y), f2bf(u1.z), f2bf(u1.w)};
        *(u16x8*)&Bg[c * 512 + l * 8] = vg;
        *(u16x8*)&Bu[c * 512 + l * 8] = vu;
      }
    }
    __syncthreads();
#pragma unroll
    for (int ksub = 0; ksub < 2; ++ksub) {
      bf16x8 a[4];
#pragma unroll
      for (int ms = 0; ms < 4; ++ms)
        a[ms] = ld_frag(&As[(((wm * 4 + ms) << 1) + ksub) * 512 + lane * 8]);
#pragma unroll
      for (int ns = 0; ns < 2; ++ns) {
        bf16x8 vg = ld_frag(&Bg[(((wn * 2 + ns) << 1) + ksub) * 512 + lane * 8]);
        bf16x8 vu = ld_frag(&Bu[(((wn * 2 + ns) << 1) + ksub) * 512 + lane * 8]);
#pragma unroll
        for (int ms = 0; ms < 4; ++ms) {
          accg[ms * 2 + ns] =
              __builtin_amdgcn_mfma_f32_16x16x32_bf16(a[ms], vg, accg[ms * 2 + ns], 0, 0, 0);
          accu[ms * 2 + ns] =
              __builtin_amdgcn_mfma_f32_16x16x32_bf16(a[ms], vu, accu[ms * 2 + ns], 0, 0, 0);
        }
      }
    }
  }
  // epilogue: h = silu(g) * u  (C/D layout: col=lane&15, row=quad*4+i)
#pragma unroll
  for (int ms = 0; ms < 4; ++ms) {
#pragma unroll
    for (int ns = 0; ns < 2; ++ns) {
      f32x4 g4 = accg[ms * 2 + ns], u4 = accu[ms * 2 + ns];
#pragma unroll
      for (int i = 0; i < 4; ++i) {
        int lrow = wm * 64 + ms * 16 + fq * 4 + i;
        int col = n0 + wn * 32 + ns * 16 + fr;
        float gv = g4[i], uv = u4[i];
        float hv = gv * uv / (1.f + __expf(-gv));
        h[(size_t)(row0 + lrow) * FDIM + col] = f2bf(hv);
      }
    }
  }
}

// ---------------- down GEMM: pv[r] = h[r] @ Wd^T (PRE) / atomic out (fallback) ------
// tile M=128, N=64, BK=64; per wave: 64x32 -> acc 32 AGPR
template <bool PRE>
__global__ __launch_bounds__(256, 4) void k_down(
    const unsigned short* __restrict__ h, const float* __restrict__ w_down32,
    const unsigned short* __restrict__ w_downb, float* __restrict__ out,
    float* __restrict__ pv, const int* __restrict__ meta,
    const int* __restrict__ ptok, const float* __restrict__ pw) {
  int nt = meta[IDX_NT];
  int rt = blockIdx.y;
  if (rt >= nt) return;
  int e = meta[IDX_TE + rt];
  int row0 = meta[IDX_TR + rt];
  int d0 = blockIdx.x * 64;

  __shared__ __align__(16) unsigned short Ah[8192], Bd[4096];
  __shared__ int stok[128];
  __shared__ float sw[128];

  int tid = threadIdx.x;
  int lane = tid & 63;
  int w = tid >> 6;
  int wm = w & 1, wn = w >> 1;
  int fr = lane & 15, fq = lane >> 4;

  if constexpr (!PRE) {
    if (tid < 128) { stok[tid] = ptok[row0 + tid]; sw[tid] = pw[row0 + tid]; }
  }

  f32x4 acc[8];
#pragma unroll
  for (int i = 0; i < 8; ++i) acc[i] = zero4();

  for (int ks = 0; ks < FDIM / 64; ++ks) {
    int k0 = ks * 64;
    if (ks) __syncthreads();
#pragma unroll
    for (int i = 0; i < 4; ++i) {
      int c = w * 4 + i;
      int msub = c >> 1, ksub = c & 1;
      const unsigned short* gp =
          h + (size_t)(row0 + msub * 16 + fr) * FDIM + (k0 + ksub * 32 + fq * 8);
      async_load16(gp, &Ah[c * 512]);
    }
    if constexpr (PRE) {
      const unsigned short* Wd = w_downb + (size_t)e * DMODEL * FDIM;
#pragma unroll
      for (int i = 0; i < 2; ++i) {
        int c = w * 2 + i;
        int drow = d0 + ((c >> 1) << 4) + fr;
        int kk = k0 + ((c & 1) << 5) + (fq << 3);
        async_load16(Wd + (size_t)drow * FDIM + kk, &Bd[c * 512]);
      }
    } else {
      const float* Wd = w_down32 + (size_t)e * DMODEL * FDIM;
#pragma unroll
      for (int i = 0; i < 2; ++i) {
        int tau = tid + 256 * i;
        int c = tau >> 6, l = tau & 63;
        int drow = d0 + ((c >> 1) << 4) + (l & 15);
        int kk = k0 + ((c & 1) << 5) + ((l >> 4) << 3);
        const float* sd = Wd + (size_t)drow * FDIM + kk;
        float4 b0 = *(const float4*)sd;
        float4 b1 = *(const float4*)(sd + 4);
        u16x8 vb = {f2bf(b0.x), f2bf(b0.y), f2bf(b0.z), f2bf(b0.w),
                    f2bf(b1.x), f2bf(b1.y), f2bf(b1.z), f2bf(b1.w)};
        *(u16x8*)&Bd[c * 512 + l * 8] = vb;
      }
    }
    __syncthreads();
#pragma unroll
    for (int ksub = 0; ksub < 2; ++ksub) {
      bf16x8 a[4];
#pragma unroll
      for (int ms = 0; ms < 4; ++ms)
        a[ms] = ld_frag(&Ah[(((wm * 4 + ms) << 1) + ksub) * 512 + lane * 8]);
#pragma unroll
      for (int ns = 0; ns < 2; ++ns) {
        bf16x8 vb = ld_frag(&Bd[(((wn * 2 + ns) << 1) + ksub) * 512 + lane * 8]);
#pragma unroll
        for (int ms = 0; ms < 4; ++ms)
          acc[ms * 2 + ns] =
              __builtin_amdgcn_mfma_f32_16x16x32_bf16(a[ms], vb, acc[ms * 2 + ns], 0, 0, 0);
      }
    }
  }
#pragma unroll
  for (int ms = 0; ms < 4; ++ms) {
#pragma unroll
    for (int ns = 0; ns < 2; ++ns) {
      f32x4 v4 = acc[ms * 2 + ns];
#pragma unroll
      for (int i = 0; i < 4; ++i) {
        int lrow = wm * 64 + ms * 16 + fq * 4 + i;
        int col = d0 + wn * 32 + ns * 16 + fr;
        if constexpr (PRE) {
          pv[(size_t)(row0 + lrow) * DMODEL + col] = v4[i];
        } else {
          int t = stok[lrow];
          if (t >= 0) atomicAdd(&out[(size_t)t * DMODEL + col], v4[i] * sw[lrow]);
        }
      }
    }
  }
}

// ---------------- combine: out[t] = w1*pv[r1] + w2*pv[r2] (no atomics) -------------
__global__ void k_combine(const float* __restrict__ pv, const int* __restrict__ rpos,
                          const float* __restrict__ tkw, float* __restrict__ out) {
  int t = blockIdx.x;
  int r1 = rpos[2 * t], r2 = rpos[2 * t + 1];
  float w1 = tkw[2 * t], w2 = tkw[2 * t + 1];
  int c = threadIdx.x << 2;
  float4 a = *(const float4*)(pv + (size_t)r1 * DMODEL + c);
  float4 b = *(const float4*)(pv + (size_t)r2 * DMODEL + c);
  float4 o;
  o.x = w1 * a.x + w2 * b.x;
  o.y = w1 * a.y + w2 * b.y;
  o.z = w1 * a.z + w2 * b.z;
  o.w = w1 * a.w + w2 * b.w;
  *(float4*)(out + (size_t)t * DMODEL + c) = o;
}

// ---------------- launch ----------------
extern "C" void kernel_launch(void* const* d_in, const int* in_sizes, int n_in,
                              void* d_out, int out_size, void* d_ws, size_t ws_size,
                              hipStream_t stream) {
  const float* x  = (const float*)d_in[0];
  const float* gw = (const float*)d_in[1];
  const float* wg = (const float*)d_in[2];
  const float* wu = (const float*)d_in[3];
  const float* wd = (const float*)d_in[4];
  float* out = (float*)d_out;
  float* logits = out + OUT_MAIN;

  char* wsb = (char*)d_ws;
  int* meta = (int*)(wsb + OFF_META);
  int* tk_e = (int*)(wsb + OFF_TKE);
  float* tk_w = (float*)(wsb + OFF_TKW);
  int* ptok = (int*)(wsb + OFF_PTOK);
  float* pw = (float*)(wsb + OFF_PW);
  unsigned short* xg = (unsigned short*)(wsb + OFF_XG);
  unsigned short* h = (unsigned short*)(wsb + OFF_H);
  unsigned short* wgb = (unsigned short*)(wsb + OFF_WGB);
  unsigned short* wub = (unsigned short*)(wsb + OFF_WUB);
  unsigned short* wdb = (unsigned short*)(wsb + OFF_WDB);
  float* pv = (float*)(wsb + OFF_PV);
  int* rpos = (int*)(wsb + OFF_RPOS);

  bool pre = ws_size >= (size_t)WS_NEED;

  hipMemsetAsync(meta, 0, 64, stream);
  hipMemsetAsync(ptok, 0xFF, MAXP * sizeof(int), stream);
  if (!pre) {
    hipMemsetAsync(out, 0, (size_t)OUT_MAIN * sizeof(float), stream);
    hipMemsetAsync(pw, 0, MAXP * sizeof(float), stream);
  }

  if (pre) {
    k_conv<<<8192, 256, 0, stream>>>(wg, wgb);
    k_conv<<<8192, 256, 0, stream>>>(wu, wub);
    k_conv<<<8192, 256, 0, stream>>>(wd, wdb);
  }

  k_router<<<TOK / 4, 256, 0, stream>>>(x, gw, logits);
  k_routing<<<TOK / 256, 256, 0, stream>>>(logits, meta, tk_e, tk_w);
  k_scan<<<1, 64, 0, stream>>>(meta);
  k_scatter<<<TOK / 256, 256, 0, stream>>>(tk_e, tk_w, meta, ptok, pw, rpos);
  k_gather<<<MAXP, 256, 0, stream>>>(x, ptok, xg);
  if (pre) {
    k_gu<true><<<dim3(FDIM / 64, MAXT), 256, 0, stream>>>(xg, wg, wu, wgb, wub, h, meta);
    k_down<true><<<dim3(DMODEL / 64, MAXT), 256, 0, stream>>>(h, wd, wdb, out, pv, meta, ptok, pw);
    k_combine<<<TOK, 256, 0, stream>>>(pv, rpos, tk_w, out);
  } else {
    k_gu<false><<<dim3(FDIM / 64, MAXT), 256, 0, stream>>>(xg, wg, wu, wgb, wub, h, meta);
    k_down<false><<<dim3(DMODEL / 64, MAXT), 256, 0, stream>>>(h, wd, wdb, out, pv, meta, ptok, pw);
  }
}

// Round 4
// 520.054 us; speedup vs baseline: 1.2287x; 1.1359x over previous
//
#include <hip/hip_runtime.h>
#include <stdint.h>

// ---------------- problem constants ----------------
#define TOK    4096
#define DMODEL 1024
#define FDIM   2048
#define NEXP   8
#define MAXP   9216            // 2*TOK + 8*128 worst-case segment padding
#define MAXT   72              // MAXP / 128 row tiles
#define OUT_MAIN (TOK * DMODEL)

// meta int indices
#define IDX_NT  24
#define IDX_TE  32
#define IDX_TR  112

// ws byte offsets
#define OFF_META 0
#define OFF_TKW  33792
#define OFF_PTOK 66560
#define OFF_PW   103424
#define OFF_XG   140288            // [MAXP][1024] bf16
#define OFF_H    19014656          // [MAXP][2048] bf16
#define OFF_WGB  56763392          // [E][F][D] bf16
#define OFF_WUB  90317824          // [E][F][D] bf16
#define OFF_WDB  123872256         // [E][D][F] bf16
#define OFF_PV   OFF_WGB           // [MAXP][1024] fp32 — aliases wgb+wub (dead after k_gu)
#define OFF_RPOS 157426688
#define WS_NEED  157459456

typedef __attribute__((ext_vector_type(8)))  __bf16 bf16x8;
typedef __attribute__((ext_vector_type(8)))  unsigned short u16x8;
typedef __attribute__((ext_vector_type(4)))  unsigned short u16x4;
typedef __attribute__((ext_vector_type(16))) float f32x16;

__device__ __forceinline__ unsigned short f2bf(float f) {
  unsigned u = __builtin_bit_cast(unsigned, f);
  u += 0x7fffu + ((u >> 16) & 1u);          // RNE
  return (unsigned short)(u >> 16);
}

__device__ __forceinline__ void async_load16(const void* g, void* l) {
  __builtin_amdgcn_global_load_lds(
      (__attribute__((address_space(1))) void*)g,
      (__attribute__((address_space(3))) void*)l, 16, 0, 0);
}

__device__ __forceinline__ bf16x8 ld_frag(const unsigned short* p) {
  return __builtin_bit_cast(bf16x8, *(const u16x8*)p);
}

// ---------------- fused prep: 3x weight conv (fp32->bf16) + router ----------------
// blocks [0,24576): conv; [24576,25600): router logits with fp64 accumulate
__global__ void k_prep(const float* __restrict__ wg, const float* __restrict__ wu,
                       const float* __restrict__ wd, unsigned short* __restrict__ wgb,
                       unsigned short* __restrict__ wub, unsigned short* __restrict__ wdb,
                       const float* __restrict__ x, const float* __restrict__ gw,
                       float* __restrict__ logits, int pre) {
  int b = blockIdx.x;
  if (b < 24576) {
    if (!pre) return;
    const float* src; unsigned short* dst; int bb;
    if (b < 8192)       { src = wg; dst = wgb; bb = b; }
    else if (b < 16384) { src = wu; dst = wub; bb = b - 8192; }
    else                { src = wd; dst = wdb; bb = b - 16384; }
    size_t i = ((size_t)bb * 256 + threadIdx.x) * 8;
    float4 a = *(const float4*)(src + i);
    float4 c = *(const float4*)(src + i + 4);
    u16x8 v = {f2bf(a.x), f2bf(a.y), f2bf(a.z), f2bf(a.w),
               f2bf(c.x), f2bf(c.y), f2bf(c.z), f2bf(c.w)};
    *(u16x8*)(dst + i) = v;
    return;
  }
  int lane = threadIdx.x & 63;
  int t = (b - 24576) * 4 + (threadIdx.x >> 6);
  double acc[NEXP];
#pragma unroll
  for (int e = 0; e < NEXP; ++e) acc[e] = 0.0;
  const float* xp = x + (size_t)t * DMODEL;
  for (int i = 0; i < DMODEL / 64; ++i) {
    int d = i * 64 + lane;
    float xv = xp[d];
#pragma unroll
    for (int e = 0; e < NEXP; ++e) acc[e] += (double)xv * (double)gw[e * DMODEL + d];
  }
#pragma unroll
  for (int e = 0; e < NEXP; ++e) {
    double v = acc[e];
#pragma unroll
    for (int off = 32; off > 0; off >>= 1) v += __shfl_down(v, off, 64);
    if (lane == 0) logits[t * NEXP + e] = (float)v;
  }
}

// ---------------- fused routing + scan + scatter (single block, 1024 thr) ----------
__global__ __launch_bounds__(1024) void k_route2(
    const float* __restrict__ logits, int* __restrict__ meta,
    float* __restrict__ tk_w, int* __restrict__ ptok, float* __restrict__ pw,
    int* __restrict__ rpos) {
  __shared__ int cnt[NEXP], cur[NEXP], seg[NEXP];
  int tid = threadIdx.x;
  if (tid < NEXP) { cnt[tid] = 0; cur[tid] = 0; }
  for (int r = tid; r < MAXP; r += 1024) ptok[r] = -1;
  __syncthreads();
  int i1[4], i2[4]; float w1v[4], w2v[4];
#pragma unroll
  for (int j = 0; j < 4; ++j) {
    int t = tid + j * 1024;
    float s[NEXP];
#pragma unroll
    for (int e = 0; e < NEXP; ++e) s[e] = logits[t * NEXP + e];
    float max1 = s[0]; int ind1 = 0;
#pragma unroll
    for (int e = 1; e < NEXP; ++e) if (s[e] > max1) { max1 = s[e]; ind1 = e; }
    float sum1 = 0.f;
#pragma unroll
    for (int e = 0; e < NEXP; ++e) {
      float f = fmaxf(fabsf(s[e]), max1);
      if (!((max1 - s[e]) / f > 0.02f)) sum1 += expf(s[e] - max1);
    }
    float max2 = -3.4e38f; int ind2 = 0;
#pragma unroll
    for (int e = 0; e < NEXP; ++e) if (e != ind1 && s[e] > max2) { max2 = s[e]; ind2 = e; }
    float sum2 = 0.f;
#pragma unroll
    for (int e = 0; e < NEXP; ++e) {
      if (e == ind1) continue;
      float f = fmaxf(fabsf(s[e]), max2);
      if (!((max2 - s[e]) / f > 0.02f)) sum2 += expf(s[e] - max2);
    }
    i1[j] = ind1; i2[j] = ind2; w1v[j] = 1.f / sum1; w2v[j] = 1.f / sum2;
    atomicAdd(&cnt[ind1], 1);
    atomicAdd(&cnt[ind2], 1);
  }
  __syncthreads();
  if (tid == 0) {
    int off = 0, nt2 = 0;
    for (int e = 0; e < NEXP; ++e) {
      seg[e] = off;
      int tiles = (cnt[e] + 127) >> 7;
      for (int j = 0; j < tiles; ++j) {
        meta[IDX_TE + nt2] = e;
        meta[IDX_TR + nt2] = off + (j << 7);
        ++nt2;
      }
      off += tiles << 7;
    }
    meta[IDX_NT] = nt2;
  }
  __syncthreads();
#pragma unroll
  for (int j = 0; j < 4; ++j) {
    int t = tid + j * 1024;
    int e1 = i1[j];
    int p1 = atomicAdd(&cur[e1], 1);
    int r1 = seg[e1] + p1;
    ptok[r1] = t; pw[r1] = w1v[j]; rpos[2 * t] = r1; tk_w[2 * t] = w1v[j];
    int e2 = i2[j];
    int p2 = atomicAdd(&cur[e2], 1);
    int r2 = seg[e2] + p2;
    ptok[r2] = t; pw[r2] = w2v[j]; rpos[2 * t + 1] = r2; tk_w[2 * t + 1] = w2v[j];
  }
}

// ---------------- gather x rows (fp32 -> bf16) in pair order; pads -> 0 ------------
__global__ void k_gather(const float* __restrict__ x, const int* __restrict__ ptok,
                         unsigned short* __restrict__ xg) {
  int r = blockIdx.x;
  int t = ptok[r];
  int c = threadIdx.x << 2;
  unsigned short o0 = 0, o1 = 0, o2 = 0, o3 = 0;
  if (t >= 0) {
    float4 v = *(const float4*)(x + ((size_t)t << 10) + c);
    o0 = f2bf(v.x); o1 = f2bf(v.y); o2 = f2bf(v.z); o3 = f2bf(v.w);
  }
  u16x4 o = {o0, o1, o2, o3};
  *(u16x4*)(xg + ((size_t)r << 10) + c) = o;
}

// ---------------- fused gate+up GEMM, 32x32x16 MFMA, tile 128x64, BK=64 ------------
// wave w: rows [wm*64,+64), cols [wn*32,+32); acc 2x f32x16 per tensor (64 AGPR)
template <bool PRE>
__global__ __launch_bounds__(256, 4) void k_gu(
    const unsigned short* __restrict__ xg,
    const float* __restrict__ wg32, const float* __restrict__ wu32,
    const unsigned short* __restrict__ wgb, const unsigned short* __restrict__ wub,
    unsigned short* __restrict__ h, const int* __restrict__ meta) {
  int nt = meta[IDX_NT];
  int rt = blockIdx.y;
  if (rt >= nt) return;
  int e = meta[IDX_TE + rt];
  int row0 = meta[IDX_TR + rt];
  int n0 = blockIdx.x * 64;

  __shared__ __align__(16) unsigned short As[8192], Bg[4096], Bu[4096];

  int tid = threadIdx.x, lane = tid & 63, w = tid >> 6;
  int wm = w & 1, wn = w >> 1;
  int l31 = lane & 31, lh = lane >> 5;

  f32x16 accg[2], accu[2];
#pragma unroll
  for (int i = 0; i < 2; ++i) {
#pragma unroll
    for (int r = 0; r < 16; ++r) { accg[i][r] = 0.f; accu[i][r] = 0.f; }
  }

  // A chunk c = msub*4 + kq; wave w stages msub = w, kq = 0..3
  const unsigned short* Abase =
      xg + (size_t)(row0 + w * 32 + l31) * DMODEL + lh * 8;
  // B chunks c = nsub*4 + kq; wave stages c0 = 2w, c1 = 2w+1
  int c0 = w * 2, c1 = c0 + 1;
  const unsigned short* G0; const unsigned short* G1;
  const unsigned short* U0; const unsigned short* U1;
  if constexpr (PRE) {
    const unsigned short* WgB = wgb + (size_t)e * FDIM * DMODEL;
    const unsigned short* WuB = wub + (size_t)e * FDIM * DMODEL;
    size_t o0 = (size_t)(n0 + ((c0 >> 2) << 5) + l31) * DMODEL + ((c0 & 3) << 4) + lh * 8;
    size_t o1 = (size_t)(n0 + ((c1 >> 2) << 5) + l31) * DMODEL + ((c1 & 3) << 4) + lh * 8;
    G0 = WgB + o0; G1 = WgB + o1; U0 = WuB + o0; U1 = WuB + o1;
  }

  for (int ks = 0; ks < DMODEL / 64; ++ks) {
    int k0 = ks * 64;
    if (ks) __syncthreads();
    async_load16(Abase + k0,      &As[(w * 4 + 0) * 512]);
    async_load16(Abase + k0 + 16, &As[(w * 4 + 1) * 512]);
    async_load16(Abase + k0 + 32, &As[(w * 4 + 2) * 512]);
    async_load16(Abase + k0 + 48, &As[(w * 4 + 3) * 512]);
    if constexpr (PRE) {
      async_load16(G0 + k0, &Bg[c0 * 512]);
      async_load16(G1 + k0, &Bg[c1 * 512]);
      async_load16(U0 + k0, &Bu[c0 * 512]);
      async_load16(U1 + k0, &Bu[c1 * 512]);
    } else {
      const float* Wg = wg32 + (size_t)e * FDIM * DMODEL;
      const float* Wu = wu32 + (size_t)e * FDIM * DMODEL;
#pragma unroll
      for (int i2 = 0; i2 < 2; ++i2) {
        int tau = tid + 256 * i2;
        int c = tau >> 6, l = tau & 63;
        int nrow = n0 + ((c >> 2) << 5) + (l & 31);
        int kk = k0 + ((c & 3) << 4) + ((l >> 5) << 3);
        const float* sg = Wg + (size_t)nrow * DMODEL + kk;
        const float* su = Wu + (size_t)nrow * DMODEL + kk;
        float4 g0 = *(const float4*)sg;
        float4 g1 = *(const float4*)(sg + 4);
        float4 u0 = *(const float4*)su;
        float4 u1 = *(const float4*)(su + 4);
        u16x8 vg = {f2bf(g0.x), f2bf(g0.y), f2bf(g0.z), f2bf(g0.w),
                    f2bf(g1.x), f2bf(g1.y), f2bf(g1.z), f2bf(g1.w)};
        u16x8 vu = {f2bf(u0.x), f2bf(u0.y), f2bf(u0.z), f2bf(u0.w),
                    f2bf(u1.x), f2bf(u1.y), f2bf(u1.z), f2bf(u1.w)};
        *(u16x8*)&Bg[c * 512 + l * 8] = vg;
        *(u16x8*)&Bu[c * 512 + l * 8] = vu;
      }
    }
    __syncthreads();
#pragma unroll
    for (int kq = 0; kq < 4; ++kq) {
      bf16x8 a0 = ld_frag(&As[((wm * 2 + 0) * 4 + kq) * 512 + lane * 8]);
      bf16x8 a1 = ld_frag(&As[((wm * 2 + 1) * 4 + kq) * 512 + lane * 8]);
      bf16x8 vg = ld_frag(&Bg[(wn * 4 + kq) * 512 + lane * 8]);
      bf16x8 vu = ld_frag(&Bu[(wn * 4 + kq) * 512 + lane * 8]);
      accg[0] = __builtin_amdgcn_mfma_f32_32x32x16_bf16(a0, vg, accg[0], 0, 0, 0);
      accg[1] = __builtin_amdgcn_mfma_f32_32x32x16_bf16(a1, vg, accg[1], 0, 0, 0);
      accu[0] = __builtin_amdgcn_mfma_f32_32x32x16_bf16(a0, vu, accu[0], 0, 0, 0);
      accu[1] = __builtin_amdgcn_mfma_f32_32x32x16_bf16(a1, vu, accu[1], 0, 0, 0);
    }
  }
  // epilogue: C/D layout col=lane&31, row=(r&3)+8*(r>>2)+4*lh
  int col = n0 + wn * 32 + l31;
#pragma unroll
  for (int mt = 0; mt < 2; ++mt) {
#pragma unroll
    for (int r = 0; r < 16; ++r) {
      int lrow = wm * 64 + mt * 32 + (r & 3) + ((r >> 2) << 3) + lh * 4;
      float gv = accg[mt][r], uv = accu[mt][r];
      float hv = gv * uv / (1.f + __expf(-gv));
      h[(size_t)(row0 + lrow) * FDIM + col] = f2bf(hv);
    }
  }
}

// ---------------- down GEMM: pv = h @ Wd^T, 32x32x16, tile 128x64, BK=64 -----------
template <bool PRE>
__global__ __launch_bounds__(256, 5) void k_down(
    const unsigned short* __restrict__ h, const float* __restrict__ wd32,
    const unsigned short* __restrict__ wdb, float* __restrict__ out,
    float* __restrict__ pv, const int* __restrict__ meta,
    const int* __restrict__ ptok, const float* __restrict__ pw) {
  int nt = meta[IDX_NT];
  int rt = blockIdx.y;
  if (rt >= nt) return;
  int e = meta[IDX_TE + rt];
  int row0 = meta[IDX_TR + rt];
  int d0 = blockIdx.x * 64;

  __shared__ __align__(16) unsigned short Ah[8192], Bd[4096];
  __shared__ int stok[128];
  __shared__ float sw[128];

  int tid = threadIdx.x, lane = tid & 63, w = tid >> 6;
  int wm = w & 1, wn = w >> 1;
  int l31 = lane & 31, lh = lane >> 5;

  if constexpr (!PRE) {
    if (tid < 128) { stok[tid] = ptok[row0 + tid]; sw[tid] = pw[row0 + tid]; }
  }

  f32x16 acc[2];
#pragma unroll
  for (int i = 0; i < 2; ++i) {
#pragma unroll
    for (int r = 0; r < 16; ++r) acc[i][r] = 0.f;
  }

  const unsigned short* Abase =
      h + (size_t)(row0 + w * 32 + l31) * FDIM + lh * 8;
  int c0 = w * 2, c1 = c0 + 1;
  const unsigned short* D0; const unsigned short* D1;
  if constexpr (PRE) {
    const unsigned short* WdB = wdb + (size_t)e * DMODEL * FDIM;
    D0 = WdB + (size_t)(d0 + ((c0 >> 2) << 5) + l31) * FDIM + ((c0 & 3) << 4) + lh * 8;
    D1 = WdB + (size_t)(d0 + ((c1 >> 2) << 5) + l31) * FDIM + ((c1 & 3) << 4) + lh * 8;
  }

  for (int ks = 0; ks < FDIM / 64; ++ks) {
    int k0 = ks * 64;
    if (ks) __syncthreads();
    async_load16(Abase + k0,      &Ah[(w * 4 + 0) * 512]);
    async_load16(Abase + k0 + 16, &Ah[(w * 4 + 1) * 512]);
    async_load16(Abase + k0 + 32, &Ah[(w * 4 + 2) * 512]);
    async_load16(Abase + k0 + 48, &Ah[(w * 4 + 3) * 512]);
    if constexpr (PRE) {
      async_load16(D0 + k0, &Bd[c0 * 512]);
      async_load16(D1 + k0, &Bd[c1 * 512]);
    } else {
      const float* Wd = wd32 + (size_t)e * DMODEL * FDIM;
#pragma unroll
      for (int i2 = 0; i2 < 2; ++i2) {
        int tau = tid + 256 * i2;
        int c = tau >> 6, l = tau & 63;
        int drow = d0 + ((c >> 2) << 5) + (l & 31);
        int kk = k0 + ((c & 3) << 4) + ((l >> 5) << 3);
        const float* sd = Wd + (size_t)drow * FDIM + kk;
        float4 b0 = *(const float4*)sd;
        float4 b1 = *(const float4*)(sd + 4);
        u16x8 vb = {f2bf(b0.x), f2bf(b0.y), f2bf(b0.z), f2bf(b0.w),
                    f2bf(b1.x), f2bf(b1.y), f2bf(b1.z), f2bf(b1.w)};
        *(u16x8*)&Bd[c * 512 + l * 8] = vb;
      }
    }
    __syncthreads();
#pragma unroll
    for (int kq = 0; kq < 4; ++kq) {
      bf16x8 a0 = ld_frag(&Ah[((wm * 2 + 0) * 4 + kq) * 512 + lane * 8]);
      bf16x8 a1 = ld_frag(&Ah[((wm * 2 + 1) * 4 + kq) * 512 + lane * 8]);
      bf16x8 vb = ld_frag(&Bd[(wn * 4 + kq) * 512 + lane * 8]);
      acc[0] = __builtin_amdgcn_mfma_f32_32x32x16_bf16(a0, vb, acc[0], 0, 0, 0);
      acc[1] = __builtin_amdgcn_mfma_f32_32x32x16_bf16(a1, vb, acc[1], 0, 0, 0);
    }
  }
  int col = d0 + wn * 32 + l31;
#pragma unroll
  for (int mt = 0; mt < 2; ++mt) {
#pragma unroll
    for (int r = 0; r < 16; ++r) {
      int lrow = wm * 64 + mt * 32 + (r & 3) + ((r >> 2) << 3) + lh * 4;
      if constexpr (PRE) {
        pv[(size_t)(row0 + lrow) * DMODEL + col] = acc[mt][r];
      } else {
        int t = stok[lrow];
        if (t >= 0) atomicAdd(&out[(size_t)t * DMODEL + col], acc[mt][r] * sw[lrow]);
      }
    }
  }
}

// ---------------- combine: out[t] = w1*pv[r1] + w2*pv[r2] --------------------------
__global__ void k_combine(const float* __restrict__ pv, const int* __restrict__ rpos,
                          const float* __restrict__ tkw, float* __restrict__ out) {
  int t = blockIdx.x;
  int r1 = rpos[2 * t], r2 = rpos[2 * t + 1];
  float w1 = tkw[2 * t], w2 = tkw[2 * t + 1];
  int c = threadIdx.x << 2;
  float4 a = *(const float4*)(pv + (size_t)r1 * DMODEL + c);
  float4 b = *(const float4*)(pv + (size_t)r2 * DMODEL + c);
  float4 o;
  o.x = w1 * a.x + w2 * b.x;
  o.y = w1 * a.y + w2 * b.y;
  o.z = w1 * a.z + w2 * b.z;
  o.w = w1 * a.w + w2 * b.w;
  *(float4*)(out + (size_t)t * DMODEL + c) = o;
}

// ---------------- launch ----------------
extern "C" void kernel_launch(void* const* d_in, const int* in_sizes, int n_in,
                              void* d_out, int out_size, void* d_ws, size_t ws_size,
                              hipStream_t stream) {
  const float* x  = (const float*)d_in[0];
  const float* gw = (const float*)d_in[1];
  const float* wg = (const float*)d_in[2];
  const float* wu = (const float*)d_in[3];
  const float* wd = (const float*)d_in[4];
  float* out = (float*)d_out;
  float* logits = out + OUT_MAIN;

  char* wsb = (char*)d_ws;
  int* meta = (int*)(wsb + OFF_META);
  float* tk_w = (float*)(wsb + OFF_TKW);
  int* ptok = (int*)(wsb + OFF_PTOK);
  float* pw = (float*)(wsb + OFF_PW);
  unsigned short* xg = (unsigned short*)(wsb + OFF_XG);
  unsigned short* h = (unsigned short*)(wsb + OFF_H);
  unsigned short* wgb = (unsigned short*)(wsb + OFF_WGB);
  unsigned short* wub = (unsigned short*)(wsb + OFF_WUB);
  unsigned short* wdb = (unsigned short*)(wsb + OFF_WDB);
  float* pv = (float*)(wsb + OFF_PV);
  int* rpos = (int*)(wsb + OFF_RPOS);

  bool pre = ws_size >= (size_t)WS_NEED;
  if (!pre) hipMemsetAsync(out, 0, (size_t)OUT_MAIN * sizeof(float), stream);

  k_prep<<<25600, 256, 0, stream>>>(wg, wu, wd, wgb, wub, wdb, x, gw, logits, (int)pre);
  k_route2<<<1, 1024, 0, stream>>>(logits, meta, tk_w, ptok, pw, rpos);
  k_gather<<<MAXP, 256, 0, stream>>>(x, ptok, xg);
  if (pre) {
    k_gu<true><<<dim3(FDIM / 64, MAXT), 256, 0, stream>>>(xg, wg, wu, wgb, wub, h, meta);
    k_down<true><<<dim3(DMODEL / 64, MAXT), 256, 0, stream>>>(h, wd, wdb, out, pv, meta, ptok, pw);
    k_combine<<<TOK, 256, 0, stream>>>(pv, rpos, tk_w, out);
  } else {
    k_gu<false><<<dim3(FDIM / 64, MAXT), 256, 0, stream>>>(xg, wg, wu, wgb, wub, h, meta);
    k_down<false><<<dim3(DMODEL / 64, MAXT), 256, 0, stream>>>(h, wd, wdb, out, pv, meta, ptok, pw);
  }
}